// Round 6
// baseline (148.648 us; speedup 1.0000x reference)
//
#include <hip/hip_runtime.h>
#include <hip/hip_bf16.h>
#include <cstdint>

// ConViT GPSA fused pipeline, bf16 MFMA throughout.
// ws (~44.9 MB): xb(7.08M) wqb/wkb/wvb/wpb(1.18M ea) Q(9.44M) K(9.44M) VT(7.08M) O(7.08M)
// posg(10.6M) overlays [xb..wvb] after gemm_qkv consumes them (wpb at 10,616,832 survives).

typedef unsigned short u16;
typedef __attribute__((ext_vector_type(8))) short bf16x8;
typedef __attribute__((ext_vector_type(4))) float f32x4;

__device__ __forceinline__ u16 f2bf(float f) {
  union { float f; uint32_t u; } v; v.f = f;
  uint32_t r = v.u + 0x7FFFu + ((v.u >> 16) & 1u);  // RNE (no NaN in this workload)
  return (u16)(r >> 16);
}
__device__ __forceinline__ float bf2f(u16 u) {
  union { uint32_t u; float f; } v; v.u = ((uint32_t)u) << 16;
  return v.f;
}

// async global->LDS, 16B per lane; LDS dest is wave-uniform base + lane*16 (linear!)
__device__ __forceinline__ void gl_lds16(const u16* g, u16* l) {
  __builtin_amdgcn_global_load_lds(
      (const __attribute__((address_space(1))) void*)g,
      (__attribute__((address_space(3))) void*)l, 16, 0, 0);
}

// ---------------- f32 -> bf16: x + all 4 weights in one dispatch ----------------
__global__ __launch_bounds__(256) void cvt_all(const float* __restrict__ x,
                                               const float* __restrict__ Wq,
                                               const float* __restrict__ Wk,
                                               const float* __restrict__ Wv,
                                               const float* __restrict__ Wp,
                                               u16* __restrict__ dst) {
  const int i = blockIdx.x * 256 + threadIdx.x;  // 1,474,560 float4 items exactly
  const float* s;
  if (i < 884736) {
    s = x + (size_t)i * 4;
  } else {
    const int j = i - 884736;
    if (j < 147456) s = Wq + (size_t)j * 4;
    else if (j < 294912) s = Wk + (size_t)(j - 147456) * 4;
    else if (j < 442368) s = Wv + (size_t)(j - 294912) * 4;
    else s = Wp + (size_t)(j - 442368) * 4;
  }
  const float4 v = *(const float4*)s;
  ushort4 o;
  o.x = f2bf(v.x); o.y = f2bf(v.y); o.z = f2bf(v.z); o.w = f2bf(v.w);
  ((ushort4*)dst)[i] = o;
}

// ---------------- g-scaled positional softmax, materialized ----------------
__global__ __launch_bounds__(256) void pos_soft(const float* __restrict__ Wpos,
                                                const float* __restrict__ bpos,
                                                const float* __restrict__ gating,
                                                u16* __restrict__ posg) {
  const int w = threadIdx.x >> 6, lane = threadIdx.x & 63;
  const int row = blockIdx.x * 4 + w;            // 0..9215  (h*576+n)
  const int h = row / 576, n = row - h * 576;
  const float w0 = Wpos[h * 3 + 0], w1 = Wpos[h * 3 + 1], w2 = Wpos[h * 3 + 2], bp = bpos[h];
  const float g = 1.f / (1.f + __expf(-gating[h]));
  const int qr = n / 24, qc = n - qr * 24;
  float vals[9], evals[9];
  float mx = -1e30f;
#pragma unroll
  for (int i = 0; i < 9; ++i) {
    const int m = i * 64 + lane;
    const int kr = m / 24, kc = m - kr * 24;
    const float dx = (float)(kc - qc), dy = (float)(kr - qr);
    const float p = w0 * dx + w1 * dy + w2 * (dx * dx + dy * dy) + bp;
    vals[i] = p;
    mx = fmaxf(mx, p);
  }
#pragma unroll
  for (int off = 1; off < 64; off <<= 1) mx = fmaxf(mx, __shfl_xor(mx, off, 64));
  float s = 0.f;
#pragma unroll
  for (int i = 0; i < 9; ++i) { evals[i] = __expf(vals[i] - mx); s += evals[i]; }
#pragma unroll
  for (int off = 1; off < 64; off <<= 1) s += __shfl_xor(s, off, 64);
  const float gi = g / s;
  u16* out = posg + (size_t)row * 576;
#pragma unroll
  for (int i = 0; i < 9; ++i) out[i * 64 + lane] = f2bf(evals[i] * gi);
}

// ---------------- unified QKV projection (C = W @ x^T per mode), K = 768 ----------------
// 2-phase double-buffered: STAGE(kt+1) issued BEFORE compute(kt); one barrier per K-step.
__global__ __launch_bounds__(256, 2) void gemm_qkv(
    const u16* __restrict__ wq, const u16* __restrict__ wk, const u16* __restrict__ wv,
    const u16* __restrict__ xb, u16* __restrict__ Qo, u16* __restrict__ Ko,
    u16* __restrict__ Vo) {
  __shared__ u16 sA[2][128 * 32];  // linear, unpadded (global_load_lds dest)
  __shared__ u16 sB[2][128 * 32];

  const int y = blockIdx.y;
  const u16* A = y == 0 ? wq : y == 1 ? wk : wv;

  const int mt = blockIdx.x / 36, nt = blockIdx.x % 36;
  const int mbase = mt * 128, nbase = nt * 128;
  const int tid = threadIdx.x;
  const int w = tid >> 6, lane = tid & 63;
  const int wr = w >> 1, wc = w & 1;
  const int lg = lane >> 4, lc = lane & 15;
  const int lrow = lane >> 2;          // staging row within 16-row band
  const int lcol = (lane & 3) * 8;     // staging col (elems)

  const u16* srcA0 = A + (size_t)(mbase + w * 16 + lrow) * 768 + lcol;
  const u16* srcA1 = srcA0 + (size_t)64 * 768;
  const u16* srcB0 = xb + (size_t)(nbase + w * 16 + lrow) * 768 + lcol;
  const u16* srcB1 = srcB0 + (size_t)64 * 768;
  const int dof = w * 512;  // 16 rows * 32 elems per wave

  const f32x4 vzero = {0.f, 0.f, 0.f, 0.f};
  f32x4 acc[4][4];
#pragma unroll
  for (int i = 0; i < 4; ++i)
#pragma unroll
    for (int j = 0; j < 4; ++j) acc[i][j] = vzero;

  // prologue: stage kt=0 into buf 0
  gl_lds16(srcA0, sA[0] + dof);
  gl_lds16(srcA1, sA[0] + 2048 + dof);
  gl_lds16(srcB0, sB[0] + dof);
  gl_lds16(srcB1, sB[0] + 2048 + dof);
  __syncthreads();

  int buf = 0;
  for (int kt = 0; kt < 24; ++kt) {
    const int nb = buf ^ 1;
    if (kt < 23) {  // issue next-tile stage FIRST (latency hides under compute)
      const int kb = (kt + 1) * 32;
      gl_lds16(srcA0 + kb, sA[nb] + dof);
      gl_lds16(srcA1 + kb, sA[nb] + 2048 + dof);
      gl_lds16(srcB0 + kb, sB[nb] + dof);
      gl_lds16(srcB1 + kb, sB[nb] + 2048 + dof);
    }
    bf16x8 av[4], bv[4];
#pragma unroll
    for (int i = 0; i < 4; ++i)
      av[i] = *(const bf16x8*)&sA[buf][(wr * 64 + i * 16 + lc) * 32 + lg * 8];
#pragma unroll
    for (int jn = 0; jn < 4; ++jn)
      bv[jn] = *(const bf16x8*)&sB[buf][(wc * 64 + jn * 16 + lc) * 32 + lg * 8];
#pragma unroll
    for (int i = 0; i < 4; ++i)
#pragma unroll
      for (int jn = 0; jn < 4; ++jn)
        acc[i][jn] = __builtin_amdgcn_mfma_f32_16x16x32_bf16(av[i], bv[jn], acc[i][jn], 0, 0, 0);
    __syncthreads();  // drains vmcnt: next buf staged; all waves done reading buf
    buf = nb;
  }

  if (y < 2) {
    const float qsc = (y == 0) ? 0.14433756729740643f : 1.0f;  // 48^-0.5 folded into Q
    u16* ob = (y == 0) ? Qo : Ko;
#pragma unroll
    for (int i = 0; i < 4; ++i) {
      const int c0 = mbase + wr * 64 + i * 16 + lg * 4;
      const int hh = c0 / 48;
      const int d0 = c0 - hh * 48;
#pragma unroll
      for (int jn = 0; jn < 4; ++jn) {
        const int bn = nbase + wc * 64 + jn * 16 + lc;
        const int bb = bn / 576;
        const int nn = bn - bb * 576;
        ushort4 o;
        o.x = f2bf(acc[i][jn][0] * qsc); o.y = f2bf(acc[i][jn][1] * qsc);
        o.z = f2bf(acc[i][jn][2] * qsc); o.w = f2bf(acc[i][jn][3] * qsc);
        *(ushort4*)&ob[(((size_t)bb * 16 + hh) * 576 + nn) * 64 + d0] = o;
      }
    }
  } else {
#pragma unroll
    for (int i = 0; i < 4; ++i) {
      const int c0 = mbase + wr * 64 + i * 16 + lg * 4;
      const int hh = c0 / 48;
      const int d0 = c0 - hh * 48;
#pragma unroll
      for (int jn = 0; jn < 4; ++jn) {
        const int bn = nbase + wc * 64 + jn * 16 + lc;
        const int bb = bn / 576;
        const int nn = bn - bb * 576;
#pragma unroll
        for (int j = 0; j < 4; ++j)
          Vo[(((size_t)bb * 16 + hh) * 48 + d0 + j) * 576 + nn] = f2bf(acc[i][jn][j]);
      }
    }
  }
}

// ---------------- pos-attention GEMM: Og[b,h,q,d] = sum_m V[b,m,d] * posg[h,q,m] ----------------
__global__ __launch_bounds__(256, 2) void pos_gemm(const u16* __restrict__ VT,
                                                   const u16* __restrict__ posg,
                                                   u16* __restrict__ O) {
  __shared__ u16 sA[2][128 * 32];
  __shared__ u16 sB[2][128 * 32];

  const int id = blockIdx.x;
  const int xcd = id & 7;
  const int local = id >> 3;        // 0..29
  const int h = xcd * 2 + local / 15;
  const int r = local % 15;
  const int mt = r / 5, nt = r % 5;

  const int mbase = mt * 128, nbase = nt * 128;
  const int tid = threadIdx.x;
  const int w = tid >> 6, lane = tid & 63;
  const int wr = w >> 1, wc = w & 1;
  const int lg = lane >> 4, lc = lane & 15;
  const int lrow = lane >> 2;
  const int lcol = (lane & 3) * 8;

  const int mA0 = mbase + w * 16 + lrow, mA1 = mA0 + 64;
  const u16* srcA0 = VT + ((size_t)((mA0 / 48) * 16 + h) * 48 + (mA0 % 48)) * 576 + lcol;
  const u16* srcA1 = VT + ((size_t)((mA1 / 48) * 16 + h) * 48 + (mA1 % 48)) * 576 + lcol;
  const u16* srcB0 = posg + (size_t)(h * 576 + nbase + w * 16 + lrow) * 576 + lcol;
  const u16* srcB1 = srcB0 + (size_t)64 * 576;
  const int dof = w * 512;

  const f32x4 vzero = {0.f, 0.f, 0.f, 0.f};
  f32x4 acc[4][4];
#pragma unroll
  for (int i = 0; i < 4; ++i)
#pragma unroll
    for (int j = 0; j < 4; ++j) acc[i][j] = vzero;

  gl_lds16(srcA0, sA[0] + dof);
  gl_lds16(srcA1, sA[0] + 2048 + dof);
  gl_lds16(srcB0, sB[0] + dof);
  gl_lds16(srcB1, sB[0] + 2048 + dof);
  __syncthreads();

  int buf = 0;
  for (int kt = 0; kt < 18; ++kt) {
    const int nb = buf ^ 1;
    if (kt < 17) {
      const int kb = (kt + 1) * 32;
      gl_lds16(srcA0 + kb, sA[nb] + dof);
      gl_lds16(srcA1 + kb, sA[nb] + 2048 + dof);
      gl_lds16(srcB0 + kb, sB[nb] + dof);
      gl_lds16(srcB1 + kb, sB[nb] + 2048 + dof);
    }
    bf16x8 av[4], bv[4];
#pragma unroll
    for (int i = 0; i < 4; ++i)
      av[i] = *(const bf16x8*)&sA[buf][(wr * 64 + i * 16 + lc) * 32 + lg * 8];
#pragma unroll
    for (int jn = 0; jn < 4; ++jn)
      bv[jn] = *(const bf16x8*)&sB[buf][(wc * 64 + jn * 16 + lc) * 32 + lg * 8];
#pragma unroll
    for (int i = 0; i < 4; ++i)
#pragma unroll
      for (int jn = 0; jn < 4; ++jn)
        acc[i][jn] = __builtin_amdgcn_mfma_f32_16x16x32_bf16(av[i], bv[jn], acc[i][jn], 0, 0, 0);
    __syncthreads();
    buf = nb;
  }

#pragma unroll
  for (int i = 0; i < 4; ++i) {
    const int c0 = mbase + wr * 64 + i * 16 + lg * 4;  // (b,d): 4 consecutive d in one head
    const int bb = c0 / 48;
    const int d0 = c0 - bb * 48;
#pragma unroll
    for (int jn = 0; jn < 4; ++jn) {
      const int q = nbase + wc * 64 + jn * 16 + lc;
      if (q < 576) {
        ushort4 o;
        o.x = f2bf(acc[i][jn][0]); o.y = f2bf(acc[i][jn][1]);
        o.z = f2bf(acc[i][jn][2]); o.w = f2bf(acc[i][jn][3]);
        *(ushort4*)&O[((size_t)(bb * 576 + q)) * 768 + h * 48 + d0] = o;
      }
    }
  }
}

// ---------------- fused patch attention (pos part pre-added in Ow) ----------------
// Structure identical to R5; __launch_bounds__(256,2) grants 256 VGPRs so the
// K/V register prefetch buffers actually stay live (R5 compiled to 84 VGPRs ->
// load serialization, ~5 memory latencies per chunk).
__global__ __launch_bounds__(256, 2) void attn_fused(
    const u16* __restrict__ Q, const u16* __restrict__ K, const u16* __restrict__ VT,
    const float* __restrict__ gating, u16* __restrict__ O) {
  const int id = blockIdx.x;
  const int b = id & 7;             // XCD-aligned (round-robin dispatch)
  const int local = id >> 3;        // 0..287
  const int h = local / 18;
  const int qt = local % 18;
  const int tid = threadIdx.x;
  const int w = tid >> 6, lane = tid & 63;
  const int qh = w >> 1, ks = w & 1;
  const int lg = lane >> 4, lc = lane & 15;
  const int bh = b * 16 + h;

  const u16* Qh = Q + (size_t)bh * 576 * 64;
  const u16* Kh = K + (size_t)bh * 576 * 64;
  const u16* Vh = VT + (size_t)bh * 48 * 576;

  __shared__ float red[2][64][13];    // split-k: 12 acc + 1 lsum (13 stride: bank-free)

  const bf16x8 zer = {0, 0, 0, 0, 0, 0, 0, 0};
  const int qbase = qt * 32 + qh * 16;
  // Q as B-operand: B[k=d][q=lc]
  const bf16x8 aq0 = *(const bf16x8*)&Qh[(qbase + lc) * 64 + lg * 8];
  bf16x8 aq1 = zer;  // d 48..63 pad: zero in-register (both operands)
  if (lg < 2) aq1 = *(const bf16x8*)&Qh[(qbase + lc) * 64 + lg * 8 + 32];

  const int kbase = ks * 288;

  bf16x8 kb[2][2][2];  // [buf][t][dhalf]; A-operand: A[key-row=lc][k=d]
#pragma unroll
  for (int t = 0; t < 2; ++t) {
    kb[0][t][0] = *(const bf16x8*)&Kh[(kbase + t * 16 + lc) * 64 + lg * 8];
    kb[0][t][1] = zer;
    if (lg < 2) kb[0][t][1] = *(const bf16x8*)&Kh[(kbase + t * 16 + lc) * 64 + lg * 8 + 32];
  }

  const f32x4 vzero = {0.f, 0.f, 0.f, 0.f};
  f32x4 accP0 = vzero, accP1 = vzero, accP2 = vzero;
  float lsum = 0.f;
  bf16x8 pfrag = zer, vp0 = zer, vp1 = zer, vp2 = zer;

  const int bpA = (((lg & 1) * 32) + lc) * 4;  // byte addr of source lane (groups 0/2)
  const int bpB = bpA + 64;                    // +16 lanes (groups 1/3)
  const bool hiK = lg >= 2;                    // this lane's keys are the t=1 (s1) band

#pragma unroll
  for (int kc = 0; kc < 9; ++kc) {
    const int cur = kc & 1;
    const int k0 = kbase + kc * 32;
    if (kc < 8) {  // prefetch next K chunk
      const int k1 = k0 + 32;
#pragma unroll
      for (int t = 0; t < 2; ++t) {
        kb[cur ^ 1][t][0] = *(const bf16x8*)&Kh[(k1 + t * 16 + lc) * 64 + lg * 8];
        kb[cur ^ 1][t][1] = zer;
        if (lg < 2) kb[cur ^ 1][t][1] = *(const bf16x8*)&Kh[(k1 + t * 16 + lc) * 64 + lg * 8 + 32];
      }
    }
    // V^T A-fragments for this chunk (consumed NEXT iteration)
    const bf16x8 vb0 = *(const bf16x8*)&Vh[lc * 576 + k0 + lg * 8];
    const bf16x8 vb1 = *(const bf16x8*)&Vh[(16 + lc) * 576 + k0 + lg * 8];
    const bf16x8 vb2 = *(const bf16x8*)&Vh[(32 + lc) * 576 + k0 + lg * 8];

    // S^T[key][q=lc]: s0 -> keys k0+lg*4+j, s1 -> keys k0+16+lg*4+j
    f32x4 s0 = vzero, s1 = vzero;
    s0 = __builtin_amdgcn_mfma_f32_16x16x32_bf16(kb[cur][0][0], aq0, s0, 0, 0, 0);
    s0 = __builtin_amdgcn_mfma_f32_16x16x32_bf16(kb[cur][0][1], aq1, s0, 0, 0, 0);
    s1 = __builtin_amdgcn_mfma_f32_16x16x32_bf16(kb[cur][1][0], aq0, s1, 0, 0, 0);
    s1 = __builtin_amdgcn_mfma_f32_16x16x32_bf16(kb[cur][1][1], aq1, s1, 0, 0, 0);

    if (kc > 0) {  // PV of previous chunk (independent of s0/s1 -> fills pipe)
      accP0 = __builtin_amdgcn_mfma_f32_16x16x32_bf16(vp0, pfrag, accP0, 0, 0, 0);
      accP1 = __builtin_amdgcn_mfma_f32_16x16x32_bf16(vp1, pfrag, accP1, 0, 0, 0);
      accP2 = __builtin_amdgcn_mfma_f32_16x16x32_bf16(vp2, pfrag, accP2, 0, 0, 0);
    }

    const float p00 = __expf(s0[0]), p01 = __expf(s0[1]);
    const float p02 = __expf(s0[2]), p03 = __expf(s0[3]);
    const float p10 = __expf(s1[0]), p11 = __expf(s1[1]);
    const float p12 = __expf(s1[2]), p13 = __expf(s1[3]);
    lsum += ((p00 + p01) + (p02 + p03)) + ((p10 + p11) + (p12 + p13));

    uint32_t c0, c1, d0, d1;  // packed bf16 pairs: c = s0-band keys, d = s1-band keys
    asm("v_cvt_pk_bf16_f32 %0, %1, %2" : "=v"(c0) : "v"(p00), "v"(p01));
    asm("v_cvt_pk_bf16_f32 %0, %1, %2" : "=v"(c1) : "v"(p02), "v"(p03));
    asm("v_cvt_pk_bf16_f32 %0, %1, %2" : "=v"(d0) : "v"(p10), "v"(p11));
    asm("v_cvt_pk_bf16_f32 %0, %1, %2" : "=v"(d1) : "v"(p12), "v"(p13));

    // Redistribute: dest lane (lg,lc) needs keys lg*8..lg*8+7 of query lc.
    const int a_c0 = __builtin_amdgcn_ds_bpermute(bpA, (int)c0);
    const int a_c1 = __builtin_amdgcn_ds_bpermute(bpA, (int)c1);
    const int a_d0 = __builtin_amdgcn_ds_bpermute(bpA, (int)d0);
    const int a_d1 = __builtin_amdgcn_ds_bpermute(bpA, (int)d1);
    const int b_c0 = __builtin_amdgcn_ds_bpermute(bpB, (int)c0);
    const int b_c1 = __builtin_amdgcn_ds_bpermute(bpB, (int)c1);
    const int b_d0 = __builtin_amdgcn_ds_bpermute(bpB, (int)d0);
    const int b_d1 = __builtin_amdgcn_ds_bpermute(bpB, (int)d1);
    union { uint32_t u[4]; bf16x8 v; } pf;
    pf.u[0] = hiK ? a_d0 : a_c0;
    pf.u[1] = hiK ? a_d1 : a_c1;
    pf.u[2] = hiK ? b_d0 : b_c0;
    pf.u[3] = hiK ? b_d1 : b_c1;
    pfrag = pf.v;
    vp0 = vb0; vp1 = vb1; vp2 = vb2;
  }
  accP0 = __builtin_amdgcn_mfma_f32_16x16x32_bf16(vp0, pfrag, accP0, 0, 0, 0);
  accP1 = __builtin_amdgcn_mfma_f32_16x16x32_bf16(vp1, pfrag, accP1, 0, 0, 0);
  accP2 = __builtin_amdgcn_mfma_f32_16x16x32_bf16(vp2, pfrag, accP2, 0, 0, 0);

  // per-query (lc) row-sum for this k-half: reduce across the 4 lane-groups
  float ls = lsum;
  ls += __shfl_xor(ls, 16, 64);
  ls += __shfl_xor(ls, 32, 64);

  if (ks == 1) {
#pragma unroll
    for (int j = 0; j < 4; ++j) {
      red[qh][lane][0 + j] = accP0[j];
      red[qh][lane][4 + j] = accP1[j];
      red[qh][lane][8 + j] = accP2[j];
    }
    red[qh][lane][12] = ls;
  }
  __syncthreads();
  if (ks == 0) {
    const float g = 1.f / (1.f + __expf(-gating[h]));
    const float linv = (1.f - g) / (ls + red[qh][lane][12]);  // uniform per lane (query lc)
    const int row = b * 576 + qbase + lc;
#pragma unroll
    for (int dt = 0; dt < 3; ++dt) {
      const f32x4 a = dt == 0 ? accP0 : dt == 1 ? accP1 : accP2;
      const size_t idx = (size_t)row * 768 + h * 48 + dt * 16 + lg * 4;
      const ushort4 old4 = *(const ushort4*)&O[idx];
      ushort4 o;
      o.x = f2bf((a[0] + red[qh][lane][dt * 4 + 0]) * linv + bf2f(old4.x));
      o.y = f2bf((a[1] + red[qh][lane][dt * 4 + 1]) * linv + bf2f(old4.y));
      o.z = f2bf((a[2] + red[qh][lane][dt * 4 + 2]) * linv + bf2f(old4.z));
      o.w = f2bf((a[3] + red[qh][lane][dt * 4 + 3]) * linv + bf2f(old4.w));
      *(ushort4*)&O[idx] = o;
    }
  }
}

// ---------------- output projection: out = O @ Wproj^T + b ----------------
__global__ __launch_bounds__(256, 2) void gemm_proj(const u16* __restrict__ A,
                                                    const u16* __restrict__ B,
                                                    float* __restrict__ of,
                                                    const float* __restrict__ bias) {
  __shared__ u16 sA[2][128 * 32];
  __shared__ u16 sB[2][128 * 32];

  const int mt = blockIdx.x / 36, nt = blockIdx.x % 36;
  const int mbase = mt * 128, nbase = nt * 128;
  const int tid = threadIdx.x;
  const int w = tid >> 6, lane = tid & 63;
  const int wr = w >> 1, wc = w & 1;
  const int lg = lane >> 4, lc = lane & 15;
  const int lrow = lane >> 2;
  const int lcol = (lane & 3) * 8;

  const u16* srcA0 = A + (size_t)(mbase + w * 16 + lrow) * 768 + lcol;
  const u16* srcA1 = srcA0 + (size_t)64 * 768;
  const u16* srcB0 = B + (size_t)(nbase + w * 16 + lrow) * 768 + lcol;
  const u16* srcB1 = srcB0 + (size_t)64 * 768;
  const int dof = w * 512;

  const f32x4 vzero = {0.f, 0.f, 0.f, 0.f};
  f32x4 acc[4][4];
#pragma unroll
  for (int i = 0; i < 4; ++i)
#pragma unroll
    for (int j = 0; j < 4; ++j) acc[i][j] = vzero;

  gl_lds16(srcA0, sA[0] + dof);
  gl_lds16(srcA1, sA[0] + 2048 + dof);
  gl_lds16(srcB0, sB[0] + dof);
  gl_lds16(srcB1, sB[0] + 2048 + dof);
  __syncthreads();

  int buf = 0;
  for (int kt = 0; kt < 24; ++kt) {
    const int nb = buf ^ 1;
    if (kt < 23) {
      const int kb = (kt + 1) * 32;
      gl_lds16(srcA0 + kb, sA[nb] + dof);
      gl_lds16(srcA1 + kb, sA[nb] + 2048 + dof);
      gl_lds16(srcB0 + kb, sB[nb] + dof);
      gl_lds16(srcB1 + kb, sB[nb] + 2048 + dof);
    }
    bf16x8 av[4], bv[4];
#pragma unroll
    for (int i = 0; i < 4; ++i)
      av[i] = *(const bf16x8*)&sA[buf][(wr * 64 + i * 16 + lc) * 32 + lg * 8];
#pragma unroll
    for (int jn = 0; jn < 4; ++jn)
      bv[jn] = *(const bf16x8*)&sB[buf][(wc * 64 + jn * 16 + lc) * 32 + lg * 8];
#pragma unroll
    for (int i = 0; i < 4; ++i)
#pragma unroll
      for (int jn = 0; jn < 4; ++jn)
        acc[i][jn] = __builtin_amdgcn_mfma_f32_16x16x32_bf16(av[i], bv[jn], acc[i][jn], 0, 0, 0);
    __syncthreads();
    buf = nb;
  }

#pragma unroll
  for (int i = 0; i < 4; ++i) {
    const int c0 = mbase + wr * 64 + i * 16 + lg * 4;
    const float4 b4 = *(const float4*)&bias[c0];
#pragma unroll
    for (int jn = 0; jn < 4; ++jn) {
      const int bn = nbase + wc * 64 + jn * 16 + lc;
      float4 o;
      o.x = acc[i][jn][0] + b4.x; o.y = acc[i][jn][1] + b4.y;
      o.z = acc[i][jn][2] + b4.z; o.w = acc[i][jn][3] + b4.w;
      *(float4*)&of[(size_t)bn * 768 + c0] = o;
    }
  }
}

// ---------------- launch ----------------
extern "C" void kernel_launch(void* const* d_in, const int* in_sizes, int n_in,
                              void* d_out, int out_size, void* d_ws, size_t ws_size,
                              hipStream_t stream) {
  const float* x      = (const float*)d_in[0];
  const float* Wq     = (const float*)d_in[1];
  const float* Wk     = (const float*)d_in[2];
  const float* Wv     = (const float*)d_in[3];
  const float* Wp     = (const float*)d_in[4];
  const float* bproj  = (const float*)d_in[5];
  const float* Wpos   = (const float*)d_in[6];
  const float* bpos   = (const float*)d_in[7];
  const float* gating = (const float*)d_in[8];
  float* out = (float*)d_out;

  char* ws = (char*)d_ws;
  u16* xb   = (u16*)(ws + 0);
  u16* wqb  = (u16*)(ws + 7077888);
  u16* wkb  = (u16*)(ws + 8257536);
  u16* wvb  = (u16*)(ws + 9437184);
  u16* wpb  = (u16*)(ws + 10616832);
  u16* Qw   = (u16*)(ws + 11796480);
  u16* Kw   = (u16*)(ws + 21233664);
  u16* VTw  = (u16*)(ws + 30670848);
  u16* Ow   = (u16*)(ws + 37748736);
  u16* posg = (u16*)(ws + 0);  // overlays xb..wvb (dead after gemm_qkv); ends exactly at wpb

  cvt_all<<<dim3(5760), dim3(256), 0, stream>>>(x, Wq, Wk, Wv, Wp, xb);
  gemm_qkv<<<dim3(216, 3), dim3(256), 0, stream>>>(wqb, wkb, wvb, xb, Qw, Kw, VTw);
  pos_soft<<<dim3(2304), dim3(256), 0, stream>>>(Wpos, bpos, gating, posg);
  pos_gemm<<<dim3(240), dim3(256), 0, stream>>>(VTw, posg, Ow);
  attn_fused<<<dim3(2304), dim3(256), 0, stream>>>(Qw, Kw, VTw, gating, Ow);
  gemm_proj<<<dim3(216), dim3(256), 0, stream>>>(wpb, Ow, out, bproj);
}

// Round 7
// 133.885 us; speedup vs baseline: 1.1103x; 1.1103x over previous
//
#include <hip/hip_runtime.h>
#include <hip/hip_bf16.h>
#include <cstdint>

// ConViT GPSA fused pipeline, bf16 MFMA throughout.
// ws (~44.9 MB): xb(7.08M) wqb/wkb/wvb/wpb(1.18M ea) Q(9.44M) K(9.44M) VT(7.08M) O(7.08M)
// posg(10.6M) overlays [xb..wvb] after gemm_qkv consumes them (wpb at 10,616,832 survives).

typedef unsigned short u16;
typedef __attribute__((ext_vector_type(8))) short bf16x8;
typedef __attribute__((ext_vector_type(4))) float f32x4;

__device__ __forceinline__ u16 f2bf(float f) {
  union { float f; uint32_t u; } v; v.f = f;
  uint32_t r = v.u + 0x7FFFu + ((v.u >> 16) & 1u);  // RNE (no NaN in this workload)
  return (u16)(r >> 16);
}
__device__ __forceinline__ float bf2f(u16 u) {
  union { uint32_t u; float f; } v; v.u = ((uint32_t)u) << 16;
  return v.f;
}

// async global->LDS, 16B per lane; LDS dest is wave-uniform base + lane*16 (linear!)
__device__ __forceinline__ void gl_lds16(const u16* g, u16* l) {
  __builtin_amdgcn_global_load_lds(
      (const __attribute__((address_space(1))) void*)g,
      (__attribute__((address_space(3))) void*)l, 16, 0, 0);
}

// ---------------- f32 -> bf16: x + all 4 weights in one dispatch ----------------
__global__ __launch_bounds__(256) void cvt_all(const float* __restrict__ x,
                                               const float* __restrict__ Wq,
                                               const float* __restrict__ Wk,
                                               const float* __restrict__ Wv,
                                               const float* __restrict__ Wp,
                                               u16* __restrict__ dst) {
  const int i = blockIdx.x * 256 + threadIdx.x;  // 1,474,560 float4 items exactly
  const float* s;
  if (i < 884736) {
    s = x + (size_t)i * 4;
  } else {
    const int j = i - 884736;
    if (j < 147456) s = Wq + (size_t)j * 4;
    else if (j < 294912) s = Wk + (size_t)(j - 147456) * 4;
    else if (j < 442368) s = Wv + (size_t)(j - 294912) * 4;
    else s = Wp + (size_t)(j - 442368) * 4;
  }
  const float4 v = *(const float4*)s;
  ushort4 o;
  o.x = f2bf(v.x); o.y = f2bf(v.y); o.z = f2bf(v.z); o.w = f2bf(v.w);
  ((ushort4*)dst)[i] = o;
}

// ---------------- g-scaled positional softmax, materialized ----------------
__global__ __launch_bounds__(256) void pos_soft(const float* __restrict__ Wpos,
                                                const float* __restrict__ bpos,
                                                const float* __restrict__ gating,
                                                u16* __restrict__ posg) {
  const int w = threadIdx.x >> 6, lane = threadIdx.x & 63;
  const int row = blockIdx.x * 4 + w;            // 0..9215  (h*576+n)
  const int h = row / 576, n = row - h * 576;
  const float w0 = Wpos[h * 3 + 0], w1 = Wpos[h * 3 + 1], w2 = Wpos[h * 3 + 2], bp = bpos[h];
  const float g = 1.f / (1.f + __expf(-gating[h]));
  const int qr = n / 24, qc = n - qr * 24;
  float vals[9], evals[9];
  float mx = -1e30f;
#pragma unroll
  for (int i = 0; i < 9; ++i) {
    const int m = i * 64 + lane;
    const int kr = m / 24, kc = m - kr * 24;
    const float dx = (float)(kc - qc), dy = (float)(kr - qr);
    const float p = w0 * dx + w1 * dy + w2 * (dx * dx + dy * dy) + bp;
    vals[i] = p;
    mx = fmaxf(mx, p);
  }
#pragma unroll
  for (int off = 1; off < 64; off <<= 1) mx = fmaxf(mx, __shfl_xor(mx, off, 64));
  float s = 0.f;
#pragma unroll
  for (int i = 0; i < 9; ++i) { evals[i] = __expf(vals[i] - mx); s += evals[i]; }
#pragma unroll
  for (int off = 1; off < 64; off <<= 1) s += __shfl_xor(s, off, 64);
  const float gi = g / s;
  u16* out = posg + (size_t)row * 576;
#pragma unroll
  for (int i = 0; i < 9; ++i) out[i * 64 + lane] = f2bf(evals[i] * gi);
}

// ---------------- unified QKV projection (C = W @ x^T per mode), K = 768 ----------------
// 2-phase double-buffered: STAGE(kt+1) issued BEFORE compute(kt); one barrier per K-step.
__global__ __launch_bounds__(256, 2) void gemm_qkv(
    const u16* __restrict__ wq, const u16* __restrict__ wk, const u16* __restrict__ wv,
    const u16* __restrict__ xb, u16* __restrict__ Qo, u16* __restrict__ Ko,
    u16* __restrict__ Vo) {
  __shared__ u16 sA[2][128 * 32];  // linear, unpadded (global_load_lds dest)
  __shared__ u16 sB[2][128 * 32];

  const int y = blockIdx.y;
  const u16* A = y == 0 ? wq : y == 1 ? wk : wv;

  const int mt = blockIdx.x / 36, nt = blockIdx.x % 36;
  const int mbase = mt * 128, nbase = nt * 128;
  const int tid = threadIdx.x;
  const int w = tid >> 6, lane = tid & 63;
  const int wr = w >> 1, wc = w & 1;
  const int lg = lane >> 4, lc = lane & 15;
  const int lrow = lane >> 2;          // staging row within 16-row band
  const int lcol = (lane & 3) * 8;     // staging col (elems)

  const u16* srcA0 = A + (size_t)(mbase + w * 16 + lrow) * 768 + lcol;
  const u16* srcA1 = srcA0 + (size_t)64 * 768;
  const u16* srcB0 = xb + (size_t)(nbase + w * 16 + lrow) * 768 + lcol;
  const u16* srcB1 = srcB0 + (size_t)64 * 768;
  const int dof = w * 512;  // 16 rows * 32 elems per wave

  const f32x4 vzero = {0.f, 0.f, 0.f, 0.f};
  f32x4 acc[4][4];
#pragma unroll
  for (int i = 0; i < 4; ++i)
#pragma unroll
    for (int j = 0; j < 4; ++j) acc[i][j] = vzero;

  // prologue: stage kt=0 into buf 0
  gl_lds16(srcA0, sA[0] + dof);
  gl_lds16(srcA1, sA[0] + 2048 + dof);
  gl_lds16(srcB0, sB[0] + dof);
  gl_lds16(srcB1, sB[0] + 2048 + dof);
  __syncthreads();

  int buf = 0;
  for (int kt = 0; kt < 24; ++kt) {
    const int nb = buf ^ 1;
    if (kt < 23) {  // issue next-tile stage FIRST (latency hides under compute)
      const int kb = (kt + 1) * 32;
      gl_lds16(srcA0 + kb, sA[nb] + dof);
      gl_lds16(srcA1 + kb, sA[nb] + 2048 + dof);
      gl_lds16(srcB0 + kb, sB[nb] + dof);
      gl_lds16(srcB1 + kb, sB[nb] + 2048 + dof);
    }
    bf16x8 av[4], bv[4];
#pragma unroll
    for (int i = 0; i < 4; ++i)
      av[i] = *(const bf16x8*)&sA[buf][(wr * 64 + i * 16 + lc) * 32 + lg * 8];
#pragma unroll
    for (int jn = 0; jn < 4; ++jn)
      bv[jn] = *(const bf16x8*)&sB[buf][(wc * 64 + jn * 16 + lc) * 32 + lg * 8];
#pragma unroll
    for (int i = 0; i < 4; ++i)
#pragma unroll
      for (int jn = 0; jn < 4; ++jn)
        acc[i][jn] = __builtin_amdgcn_mfma_f32_16x16x32_bf16(av[i], bv[jn], acc[i][jn], 0, 0, 0);
    __syncthreads();  // drains vmcnt: next buf staged; all waves done reading buf
    buf = nb;
  }

  if (y < 2) {
    const float qsc = (y == 0) ? 0.14433756729740643f : 1.0f;  // 48^-0.5 folded into Q
    u16* ob = (y == 0) ? Qo : Ko;
#pragma unroll
    for (int i = 0; i < 4; ++i) {
      const int c0 = mbase + wr * 64 + i * 16 + lg * 4;
      const int hh = c0 / 48;
      const int d0 = c0 - hh * 48;
#pragma unroll
      for (int jn = 0; jn < 4; ++jn) {
        const int bn = nbase + wc * 64 + jn * 16 + lc;
        const int bb = bn / 576;
        const int nn = bn - bb * 576;
        ushort4 o;
        o.x = f2bf(acc[i][jn][0] * qsc); o.y = f2bf(acc[i][jn][1] * qsc);
        o.z = f2bf(acc[i][jn][2] * qsc); o.w = f2bf(acc[i][jn][3] * qsc);
        *(ushort4*)&ob[(((size_t)bb * 16 + hh) * 576 + nn) * 64 + d0] = o;
      }
    }
  } else {
#pragma unroll
    for (int i = 0; i < 4; ++i) {
      const int c0 = mbase + wr * 64 + i * 16 + lg * 4;
      const int hh = c0 / 48;
      const int d0 = c0 - hh * 48;
#pragma unroll
      for (int jn = 0; jn < 4; ++jn) {
        const int bn = nbase + wc * 64 + jn * 16 + lc;
        const int bb = bn / 576;
        const int nn = bn - bb * 576;
#pragma unroll
        for (int j = 0; j < 4; ++j)
          Vo[(((size_t)bb * 16 + hh) * 48 + d0 + j) * 576 + nn] = f2bf(acc[i][jn][j]);
      }
    }
  }
}

// ---------------- pos-attention GEMM: Og[b,h,q,d] = sum_m V[b,m,d] * posg[h,q,m] ----------------
__global__ __launch_bounds__(256, 2) void pos_gemm(const u16* __restrict__ VT,
                                                   const u16* __restrict__ posg,
                                                   u16* __restrict__ O) {
  __shared__ u16 sA[2][128 * 32];
  __shared__ u16 sB[2][128 * 32];

  const int id = blockIdx.x;
  const int xcd = id & 7;
  const int local = id >> 3;        // 0..29
  const int h = xcd * 2 + local / 15;
  const int r = local % 15;
  const int mt = r / 5, nt = r % 5;

  const int mbase = mt * 128, nbase = nt * 128;
  const int tid = threadIdx.x;
  const int w = tid >> 6, lane = tid & 63;
  const int wr = w >> 1, wc = w & 1;
  const int lg = lane >> 4, lc = lane & 15;
  const int lrow = lane >> 2;
  const int lcol = (lane & 3) * 8;

  const int mA0 = mbase + w * 16 + lrow, mA1 = mA0 + 64;
  const u16* srcA0 = VT + ((size_t)((mA0 / 48) * 16 + h) * 48 + (mA0 % 48)) * 576 + lcol;
  const u16* srcA1 = VT + ((size_t)((mA1 / 48) * 16 + h) * 48 + (mA1 % 48)) * 576 + lcol;
  const u16* srcB0 = posg + (size_t)(h * 576 + nbase + w * 16 + lrow) * 576 + lcol;
  const u16* srcB1 = srcB0 + (size_t)64 * 576;
  const int dof = w * 512;

  const f32x4 vzero = {0.f, 0.f, 0.f, 0.f};
  f32x4 acc[4][4];
#pragma unroll
  for (int i = 0; i < 4; ++i)
#pragma unroll
    for (int j = 0; j < 4; ++j) acc[i][j] = vzero;

  gl_lds16(srcA0, sA[0] + dof);
  gl_lds16(srcA1, sA[0] + 2048 + dof);
  gl_lds16(srcB0, sB[0] + dof);
  gl_lds16(srcB1, sB[0] + 2048 + dof);
  __syncthreads();

  int buf = 0;
  for (int kt = 0; kt < 18; ++kt) {
    const int nb = buf ^ 1;
    if (kt < 17) {
      const int kb = (kt + 1) * 32;
      gl_lds16(srcA0 + kb, sA[nb] + dof);
      gl_lds16(srcA1 + kb, sA[nb] + 2048 + dof);
      gl_lds16(srcB0 + kb, sB[nb] + dof);
      gl_lds16(srcB1 + kb, sB[nb] + 2048 + dof);
    }
    bf16x8 av[4], bv[4];
#pragma unroll
    for (int i = 0; i < 4; ++i)
      av[i] = *(const bf16x8*)&sA[buf][(wr * 64 + i * 16 + lc) * 32 + lg * 8];
#pragma unroll
    for (int jn = 0; jn < 4; ++jn)
      bv[jn] = *(const bf16x8*)&sB[buf][(wc * 64 + jn * 16 + lc) * 32 + lg * 8];
#pragma unroll
    for (int i = 0; i < 4; ++i)
#pragma unroll
      for (int jn = 0; jn < 4; ++jn)
        acc[i][jn] = __builtin_amdgcn_mfma_f32_16x16x32_bf16(av[i], bv[jn], acc[i][jn], 0, 0, 0);
    __syncthreads();
    buf = nb;
  }

#pragma unroll
  for (int i = 0; i < 4; ++i) {
    const int c0 = mbase + wr * 64 + i * 16 + lg * 4;  // (b,d): 4 consecutive d in one head
    const int bb = c0 / 48;
    const int d0 = c0 - bb * 48;
#pragma unroll
    for (int jn = 0; jn < 4; ++jn) {
      const int q = nbase + wc * 64 + jn * 16 + lc;
      if (q < 576) {
        ushort4 o;
        o.x = f2bf(acc[i][jn][0]); o.y = f2bf(acc[i][jn][1]);
        o.z = f2bf(acc[i][jn][2]); o.w = f2bf(acc[i][jn][3]);
        *(ushort4*)&O[((size_t)(bb * 576 + q)) * 768 + h * 48 + d0] = o;
      }
    }
  }
}

// ---------------- fused patch attention (pos part pre-added in Ow) ----------------
// 64 queries/block: wave (qh,ks) handles TWO 16-query sub-tiles sharing one K/V load
// stream -> per-chunk load count unchanged, chunk count halved (grid 2304 -> 1152).
// Q/K pad d48..63 is zeroed by memset -> ALL loads unconditional (no exec-mask setting
// around loads; R3-R6's `if(lg<2)` conditional loads are a suspected schedule pin).
__global__ __launch_bounds__(256, 2) void attn_fused(
    const u16* __restrict__ Q, const u16* __restrict__ K, const u16* __restrict__ VT,
    const float* __restrict__ gating, u16* __restrict__ O) {
  const int id = blockIdx.x;
  const int b = id & 7;             // XCD-aligned (round-robin dispatch)
  const int local = id >> 3;        // 0..143
  const int h = local / 9;
  const int qt = local % 9;
  const int tid = threadIdx.x;
  const int w = tid >> 6, lane = tid & 63;
  const int qh = w >> 1, ks = w & 1;
  const int lg = lane >> 4, lc = lane & 15;
  const int bh = b * 16 + h;

  const u16* Qh = Q + (size_t)bh * 576 * 64;
  const u16* Kh = K + (size_t)bh * 576 * 64;
  const u16* Vh = VT + (size_t)bh * 48 * 576;

  __shared__ float red[4][64][13];    // split-k: [qh*2+qs][lane][12 acc + 1 lsum]

  const bf16x8 zer = {0, 0, 0, 0, 0, 0, 0, 0};
  const int qbase = qt * 64 + qh * 32;
  // Q as B-operand: B[k=d][q=lc]; pad rows are zero (memset) -> unconditional
  bf16x8 aq0_0 = *(const bf16x8*)&Qh[(qbase + lc) * 64 + lg * 8];
  bf16x8 aq0_1 = *(const bf16x8*)&Qh[(qbase + lc) * 64 + 32 + lg * 8];
  bf16x8 aq1_0 = *(const bf16x8*)&Qh[(qbase + 16 + lc) * 64 + lg * 8];
  bf16x8 aq1_1 = *(const bf16x8*)&Qh[(qbase + 16 + lc) * 64 + 32 + lg * 8];

  const int kbase = ks * 288;

  bf16x8 kb[2][2][2];  // [buf][t][dhalf]; A-operand: A[key-row=lc][k=d]
#pragma unroll
  for (int t = 0; t < 2; ++t) {
    kb[0][t][0] = *(const bf16x8*)&Kh[(kbase + t * 16 + lc) * 64 + lg * 8];
    kb[0][t][1] = *(const bf16x8*)&Kh[(kbase + t * 16 + lc) * 64 + 32 + lg * 8];
  }

  const f32x4 vzero = {0.f, 0.f, 0.f, 0.f};
  f32x4 accP[2][3];
#pragma unroll
  for (int qs = 0; qs < 2; ++qs)
#pragma unroll
    for (int dt = 0; dt < 3; ++dt) accP[qs][dt] = vzero;
  float lsum[2] = {0.f, 0.f};
  bf16x8 pfrag[2] = {zer, zer};
  bf16x8 vp0 = zer, vp1 = zer, vp2 = zer;

  const int bpA = (((lg & 1) * 32) + lc) * 4;  // source lane byte addr (groups 0/2)
  const int bpB = bpA + 64;                    // +16 lanes (groups 1/3)
  const bool hiK = lg >= 2;                    // this lane's keys come from the s1 band

#pragma unroll
  for (int kc = 0; kc < 9; ++kc) {
    const int cur = kc & 1;
    const int k0 = kbase + kc * 32;
    if (kc < 8) {  // prefetch next K chunk (unconditional, full 64-d rows incl. zero pad)
      const int k1 = k0 + 32;
#pragma unroll
      for (int t = 0; t < 2; ++t) {
        kb[cur ^ 1][t][0] = *(const bf16x8*)&Kh[(k1 + t * 16 + lc) * 64 + lg * 8];
        kb[cur ^ 1][t][1] = *(const bf16x8*)&Kh[(k1 + t * 16 + lc) * 64 + 32 + lg * 8];
      }
    }
    // V^T A-fragments for this chunk (consumed NEXT iteration)
    const bf16x8 vb0 = *(const bf16x8*)&Vh[lc * 576 + k0 + lg * 8];
    const bf16x8 vb1 = *(const bf16x8*)&Vh[(16 + lc) * 576 + k0 + lg * 8];
    const bf16x8 vb2 = *(const bf16x8*)&Vh[(32 + lc) * 576 + k0 + lg * 8];

    // S^T[key][q=lc] for both q-subtiles (shared kb)
    f32x4 s00 = vzero, s01 = vzero, s10 = vzero, s11 = vzero;
    s00 = __builtin_amdgcn_mfma_f32_16x16x32_bf16(kb[cur][0][0], aq0_0, s00, 0, 0, 0);
    s00 = __builtin_amdgcn_mfma_f32_16x16x32_bf16(kb[cur][0][1], aq0_1, s00, 0, 0, 0);
    s01 = __builtin_amdgcn_mfma_f32_16x16x32_bf16(kb[cur][1][0], aq0_0, s01, 0, 0, 0);
    s01 = __builtin_amdgcn_mfma_f32_16x16x32_bf16(kb[cur][1][1], aq0_1, s01, 0, 0, 0);
    s10 = __builtin_amdgcn_mfma_f32_16x16x32_bf16(kb[cur][0][0], aq1_0, s10, 0, 0, 0);
    s10 = __builtin_amdgcn_mfma_f32_16x16x32_bf16(kb[cur][0][1], aq1_1, s10, 0, 0, 0);
    s11 = __builtin_amdgcn_mfma_f32_16x16x32_bf16(kb[cur][1][0], aq1_0, s11, 0, 0, 0);
    s11 = __builtin_amdgcn_mfma_f32_16x16x32_bf16(kb[cur][1][1], aq1_1, s11, 0, 0, 0);

    if (kc > 0) {  // PV of previous chunk (independent of s* -> fills pipe)
#pragma unroll
      for (int qs = 0; qs < 2; ++qs) {
        accP[qs][0] = __builtin_amdgcn_mfma_f32_16x16x32_bf16(vp0, pfrag[qs], accP[qs][0], 0, 0, 0);
        accP[qs][1] = __builtin_amdgcn_mfma_f32_16x16x32_bf16(vp1, pfrag[qs], accP[qs][1], 0, 0, 0);
        accP[qs][2] = __builtin_amdgcn_mfma_f32_16x16x32_bf16(vp2, pfrag[qs], accP[qs][2], 0, 0, 0);
      }
    }

#pragma unroll
    for (int qs = 0; qs < 2; ++qs) {
      const f32x4 s0 = qs == 0 ? s00 : s10;
      const f32x4 s1 = qs == 0 ? s01 : s11;
      const float p00 = __expf(s0[0]), p01 = __expf(s0[1]);
      const float p02 = __expf(s0[2]), p03 = __expf(s0[3]);
      const float p10 = __expf(s1[0]), p11 = __expf(s1[1]);
      const float p12 = __expf(s1[2]), p13 = __expf(s1[3]);
      lsum[qs] += ((p00 + p01) + (p02 + p03)) + ((p10 + p11) + (p12 + p13));

      uint32_t c0, c1, d0, d1;  // packed bf16 pairs: c = s0-band keys, d = s1-band keys
      asm("v_cvt_pk_bf16_f32 %0, %1, %2" : "=v"(c0) : "v"(p00), "v"(p01));
      asm("v_cvt_pk_bf16_f32 %0, %1, %2" : "=v"(c1) : "v"(p02), "v"(p03));
      asm("v_cvt_pk_bf16_f32 %0, %1, %2" : "=v"(d0) : "v"(p10), "v"(p11));
      asm("v_cvt_pk_bf16_f32 %0, %1, %2" : "=v"(d1) : "v"(p12), "v"(p13));

      // Redistribute: dest lane (lg,lc) needs keys lg*8..lg*8+7 of query lc.
      const int a_c0 = __builtin_amdgcn_ds_bpermute(bpA, (int)c0);
      const int a_c1 = __builtin_amdgcn_ds_bpermute(bpA, (int)c1);
      const int a_d0 = __builtin_amdgcn_ds_bpermute(bpA, (int)d0);
      const int a_d1 = __builtin_amdgcn_ds_bpermute(bpA, (int)d1);
      const int b_c0 = __builtin_amdgcn_ds_bpermute(bpB, (int)c0);
      const int b_c1 = __builtin_amdgcn_ds_bpermute(bpB, (int)c1);
      const int b_d0 = __builtin_amdgcn_ds_bpermute(bpB, (int)d0);
      const int b_d1 = __builtin_amdgcn_ds_bpermute(bpB, (int)d1);
      union { uint32_t u[4]; bf16x8 v; } pf;
      pf.u[0] = hiK ? a_d0 : a_c0;
      pf.u[1] = hiK ? a_d1 : a_c1;
      pf.u[2] = hiK ? b_d0 : b_c0;
      pf.u[3] = hiK ? b_d1 : b_c1;
      pfrag[qs] = pf.v;
    }
    vp0 = vb0; vp1 = vb1; vp2 = vb2;
  }
#pragma unroll
  for (int qs = 0; qs < 2; ++qs) {
    accP[qs][0] = __builtin_amdgcn_mfma_f32_16x16x32_bf16(vp0, pfrag[qs], accP[qs][0], 0, 0, 0);
    accP[qs][1] = __builtin_amdgcn_mfma_f32_16x16x32_bf16(vp1, pfrag[qs], accP[qs][1], 0, 0, 0);
    accP[qs][2] = __builtin_amdgcn_mfma_f32_16x16x32_bf16(vp2, pfrag[qs], accP[qs][2], 0, 0, 0);
  }

  // per-query (lc) row-sum for this k-half: reduce across the 4 lane-groups
  float ls[2];
#pragma unroll
  for (int qs = 0; qs < 2; ++qs) {
    float t = lsum[qs];
    t += __shfl_xor(t, 16, 64);
    t += __shfl_xor(t, 32, 64);
    ls[qs] = t;
  }

  if (ks == 1) {
#pragma unroll
    for (int qs = 0; qs < 2; ++qs) {
#pragma unroll
      for (int j = 0; j < 4; ++j) {
        red[qh * 2 + qs][lane][0 + j] = accP[qs][0][j];
        red[qh * 2 + qs][lane][4 + j] = accP[qs][1][j];
        red[qh * 2 + qs][lane][8 + j] = accP[qs][2][j];
      }
      red[qh * 2 + qs][lane][12] = ls[qs];
    }
  }
  __syncthreads();
  if (ks == 0) {
    const float g = 1.f / (1.f + __expf(-gating[h]));
#pragma unroll
    for (int qs = 0; qs < 2; ++qs) {
      const float linv = (1.f - g) / (ls[qs] + red[qh * 2 + qs][lane][12]);
      const int row = b * 576 + qbase + qs * 16 + lc;
#pragma unroll
      for (int dt = 0; dt < 3; ++dt) {
        const f32x4 a = accP[qs][dt];
        const size_t idx = (size_t)row * 768 + h * 48 + dt * 16 + lg * 4;
        const ushort4 old4 = *(const ushort4*)&O[idx];
        ushort4 o;
        o.x = f2bf((a[0] + red[qh * 2 + qs][lane][dt * 4 + 0]) * linv + bf2f(old4.x));
        o.y = f2bf((a[1] + red[qh * 2 + qs][lane][dt * 4 + 1]) * linv + bf2f(old4.y));
        o.z = f2bf((a[2] + red[qh * 2 + qs][lane][dt * 4 + 2]) * linv + bf2f(old4.z));
        o.w = f2bf((a[3] + red[qh * 2 + qs][lane][dt * 4 + 3]) * linv + bf2f(old4.w));
        *(ushort4*)&O[idx] = o;
      }
    }
  }
}

// ---------------- output projection: out = O @ Wproj^T + b ----------------
__global__ __launch_bounds__(256, 2) void gemm_proj(const u16* __restrict__ A,
                                                    const u16* __restrict__ B,
                                                    float* __restrict__ of,
                                                    const float* __restrict__ bias) {
  __shared__ u16 sA[2][128 * 32];
  __shared__ u16 sB[2][128 * 32];

  const int mt = blockIdx.x / 36, nt = blockIdx.x % 36;
  const int mbase = mt * 128, nbase = nt * 128;
  const int tid = threadIdx.x;
  const int w = tid >> 6, lane = tid & 63;
  const int wr = w >> 1, wc = w & 1;
  const int lg = lane >> 4, lc = lane & 15;
  const int lrow = lane >> 2;
  const int lcol = (lane & 3) * 8;

  const u16* srcA0 = A + (size_t)(mbase + w * 16 + lrow) * 768 + lcol;
  const u16* srcA1 = srcA0 + (size_t)64 * 768;
  const u16* srcB0 = B + (size_t)(nbase + w * 16 + lrow) * 768 + lcol;
  const u16* srcB1 = srcB0 + (size_t)64 * 768;
  const int dof = w * 512;

  const f32x4 vzero = {0.f, 0.f, 0.f, 0.f};
  f32x4 acc[4][4];
#pragma unroll
  for (int i = 0; i < 4; ++i)
#pragma unroll
    for (int j = 0; j < 4; ++j) acc[i][j] = vzero;

  gl_lds16(srcA0, sA[0] + dof);
  gl_lds16(srcA1, sA[0] + 2048 + dof);
  gl_lds16(srcB0, sB[0] + dof);
  gl_lds16(srcB1, sB[0] + 2048 + dof);
  __syncthreads();

  int buf = 0;
  for (int kt = 0; kt < 24; ++kt) {
    const int nb = buf ^ 1;
    if (kt < 23) {
      const int kb = (kt + 1) * 32;
      gl_lds16(srcA0 + kb, sA[nb] + dof);
      gl_lds16(srcA1 + kb, sA[nb] + 2048 + dof);
      gl_lds16(srcB0 + kb, sB[nb] + dof);
      gl_lds16(srcB1 + kb, sB[nb] + 2048 + dof);
    }
    bf16x8 av[4], bv[4];
#pragma unroll
    for (int i = 0; i < 4; ++i)
      av[i] = *(const bf16x8*)&sA[buf][(wr * 64 + i * 16 + lc) * 32 + lg * 8];
#pragma unroll
    for (int jn = 0; jn < 4; ++jn)
      bv[jn] = *(const bf16x8*)&sB[buf][(wc * 64 + jn * 16 + lc) * 32 + lg * 8];
#pragma unroll
    for (int i = 0; i < 4; ++i)
#pragma unroll
      for (int jn = 0; jn < 4; ++jn)
        acc[i][jn] = __builtin_amdgcn_mfma_f32_16x16x32_bf16(av[i], bv[jn], acc[i][jn], 0, 0, 0);
    __syncthreads();
    buf = nb;
  }

#pragma unroll
  for (int i = 0; i < 4; ++i) {
    const int c0 = mbase + wr * 64 + i * 16 + lg * 4;
    const float4 b4 = *(const float4*)&bias[c0];
#pragma unroll
    for (int jn = 0; jn < 4; ++jn) {
      const int bn = nbase + wc * 64 + jn * 16 + lc;
      float4 o;
      o.x = acc[i][jn][0] + b4.x; o.y = acc[i][jn][1] + b4.y;
      o.z = acc[i][jn][2] + b4.z; o.w = acc[i][jn][3] + b4.w;
      *(float4*)&of[(size_t)bn * 768 + c0] = o;
    }
  }
}

// ---------------- launch ----------------
extern "C" void kernel_launch(void* const* d_in, const int* in_sizes, int n_in,
                              void* d_out, int out_size, void* d_ws, size_t ws_size,
                              hipStream_t stream) {
  const float* x      = (const float*)d_in[0];
  const float* Wq     = (const float*)d_in[1];
  const float* Wk     = (const float*)d_in[2];
  const float* Wv     = (const float*)d_in[3];
  const float* Wp     = (const float*)d_in[4];
  const float* bproj  = (const float*)d_in[5];
  const float* Wpos   = (const float*)d_in[6];
  const float* bpos   = (const float*)d_in[7];
  const float* gating = (const float*)d_in[8];
  float* out = (float*)d_out;

  char* ws = (char*)d_ws;
  u16* xb   = (u16*)(ws + 0);
  u16* wqb  = (u16*)(ws + 7077888);
  u16* wkb  = (u16*)(ws + 8257536);
  u16* wvb  = (u16*)(ws + 9437184);
  u16* wpb  = (u16*)(ws + 10616832);
  u16* Qw   = (u16*)(ws + 11796480);
  u16* Kw   = (u16*)(ws + 21233664);
  u16* VTw  = (u16*)(ws + 30670848);
  u16* Ow   = (u16*)(ws + 37748736);
  u16* posg = (u16*)(ws + 0);  // overlays xb..wvb (dead after gemm_qkv); ends exactly at wpb

  cvt_all<<<dim3(5760), dim3(256), 0, stream>>>(x, Wq, Wk, Wv, Wp, xb);
  // zero Q+K (contiguous) so head-dim pad 48..63 is exact zero -> attn loads unconditional
  hipMemsetAsync(Qw, 0, 18874368, stream);
  gemm_qkv<<<dim3(216, 3), dim3(256), 0, stream>>>(wqb, wkb, wvb, xb, Qw, Kw, VTw);
  pos_soft<<<dim3(2304), dim3(256), 0, stream>>>(Wpos, bpos, gating, posg);
  pos_gemm<<<dim3(240), dim3(256), 0, stream>>>(VTw, posg, Ow);
  attn_fused<<<dim3(1152), dim3(256), 0, stream>>>(Qw, Kw, VTw, gating, Ow);
  gemm_proj<<<dim3(216), dim3(256), 0, stream>>>(wpb, Ow, out, bproj);
}

// Round 8
// 112.970 us; speedup vs baseline: 1.3158x; 1.1851x over previous
//
#include <hip/hip_runtime.h>
#include <hip/hip_bf16.h>
#include <cstdint>

// ConViT GPSA fused pipeline, bf16 MFMA throughout.
// ws (~44.9 MB): xb(7.08M) wqb/wkb/wvb/wpb(1.18M ea) Q(9.44M) K(9.44M) VT(7.08M) O(7.08M)
// posg(10.6M) overlays [xb..wvb] after gemm_qkv consumes them (wpb at 10,616,832 survives).

typedef unsigned short u16;
typedef __attribute__((ext_vector_type(8))) short bf16x8;
typedef __attribute__((ext_vector_type(4))) float f32x4;

__device__ __forceinline__ u16 f2bf(float f) {
  union { float f; uint32_t u; } v; v.f = f;
  uint32_t r = v.u + 0x7FFFu + ((v.u >> 16) & 1u);  // RNE (no NaN in this workload)
  return (u16)(r >> 16);
}
__device__ __forceinline__ float bf2f(u16 u) {
  union { uint32_t u; float f; } v; v.u = ((uint32_t)u) << 16;
  return v.f;
}

// async global->LDS, 16B per lane; LDS dest is wave-uniform base + lane*16 (linear!)
__device__ __forceinline__ void gl_lds16(const u16* g, u16* l) {
  __builtin_amdgcn_global_load_lds(
      (const __attribute__((address_space(1))) void*)g,
      (__attribute__((address_space(3))) void*)l, 16, 0, 0);
}

// ---------------- f32 -> bf16: x + all 4 weights in one dispatch ----------------
__global__ __launch_bounds__(256) void cvt_all(const float* __restrict__ x,
                                               const float* __restrict__ Wq,
                                               const float* __restrict__ Wk,
                                               const float* __restrict__ Wv,
                                               const float* __restrict__ Wp,
                                               u16* __restrict__ dst) {
  const int i = blockIdx.x * 256 + threadIdx.x;  // 1,474,560 float4 items exactly
  const float* s;
  if (i < 884736) {
    s = x + (size_t)i * 4;
  } else {
    const int j = i - 884736;
    if (j < 147456) s = Wq + (size_t)j * 4;
    else if (j < 294912) s = Wk + (size_t)(j - 147456) * 4;
    else if (j < 442368) s = Wv + (size_t)(j - 294912) * 4;
    else s = Wp + (size_t)(j - 442368) * 4;
  }
  const float4 v = *(const float4*)s;
  ushort4 o;
  o.x = f2bf(v.x); o.y = f2bf(v.y); o.z = f2bf(v.z); o.w = f2bf(v.w);
  ((ushort4*)dst)[i] = o;
}

// ---------------- g-scaled positional softmax, materialized ----------------
__global__ __launch_bounds__(256) void pos_soft(const float* __restrict__ Wpos,
                                                const float* __restrict__ bpos,
                                                const float* __restrict__ gating,
                                                u16* __restrict__ posg) {
  const int w = threadIdx.x >> 6, lane = threadIdx.x & 63;
  const int row = blockIdx.x * 4 + w;            // 0..9215  (h*576+n)
  const int h = row / 576, n = row - h * 576;
  const float w0 = Wpos[h * 3 + 0], w1 = Wpos[h * 3 + 1], w2 = Wpos[h * 3 + 2], bp = bpos[h];
  const float g = 1.f / (1.f + __expf(-gating[h]));
  const int qr = n / 24, qc = n - qr * 24;
  float vals[9], evals[9];
  float mx = -1e30f;
#pragma unroll
  for (int i = 0; i < 9; ++i) {
    const int m = i * 64 + lane;
    const int kr = m / 24, kc = m - kr * 24;
    const float dx = (float)(kc - qc), dy = (float)(kr - qr);
    const float p = w0 * dx + w1 * dy + w2 * (dx * dx + dy * dy) + bp;
    vals[i] = p;
    mx = fmaxf(mx, p);
  }
#pragma unroll
  for (int off = 1; off < 64; off <<= 1) mx = fmaxf(mx, __shfl_xor(mx, off, 64));
  float s = 0.f;
#pragma unroll
  for (int i = 0; i < 9; ++i) { evals[i] = __expf(vals[i] - mx); s += evals[i]; }
#pragma unroll
  for (int off = 1; off < 64; off <<= 1) s += __shfl_xor(s, off, 64);
  const float gi = g / s;
  u16* out = posg + (size_t)row * 576;
#pragma unroll
  for (int i = 0; i < 9; ++i) out[i * 64 + lane] = f2bf(evals[i] * gi);
}

// ---------------- unified QKV projection (C = W @ x^T per mode), K = 768 ----------------
// 2-phase double-buffered. Q/K epilogue also zero-fills the d48..63 head pad (the block
// owning channel c0 % 48 == 44 writes it) -> no separate 19MB memset dispatch.
__global__ __launch_bounds__(256, 2) void gemm_qkv(
    const u16* __restrict__ wq, const u16* __restrict__ wk, const u16* __restrict__ wv,
    const u16* __restrict__ xb, u16* __restrict__ Qo, u16* __restrict__ Ko,
    u16* __restrict__ Vo) {
  __shared__ u16 sA[2][128 * 32];  // linear, unpadded (global_load_lds dest)
  __shared__ u16 sB[2][128 * 32];

  const int y = blockIdx.y;
  const u16* A = y == 0 ? wq : y == 1 ? wk : wv;

  const int mt = blockIdx.x / 36, nt = blockIdx.x % 36;
  const int mbase = mt * 128, nbase = nt * 128;
  const int tid = threadIdx.x;
  const int w = tid >> 6, lane = tid & 63;
  const int wr = w >> 1, wc = w & 1;
  const int lg = lane >> 4, lc = lane & 15;
  const int lrow = lane >> 2;          // staging row within 16-row band
  const int lcol = (lane & 3) * 8;     // staging col (elems)

  const u16* srcA0 = A + (size_t)(mbase + w * 16 + lrow) * 768 + lcol;
  const u16* srcA1 = srcA0 + (size_t)64 * 768;
  const u16* srcB0 = xb + (size_t)(nbase + w * 16 + lrow) * 768 + lcol;
  const u16* srcB1 = srcB0 + (size_t)64 * 768;
  const int dof = w * 512;  // 16 rows * 32 elems per wave

  const f32x4 vzero = {0.f, 0.f, 0.f, 0.f};
  f32x4 acc[4][4];
#pragma unroll
  for (int i = 0; i < 4; ++i)
#pragma unroll
    for (int j = 0; j < 4; ++j) acc[i][j] = vzero;

  // prologue: stage kt=0 into buf 0
  gl_lds16(srcA0, sA[0] + dof);
  gl_lds16(srcA1, sA[0] + 2048 + dof);
  gl_lds16(srcB0, sB[0] + dof);
  gl_lds16(srcB1, sB[0] + 2048 + dof);
  __syncthreads();

  int buf = 0;
  for (int kt = 0; kt < 24; ++kt) {
    const int nb = buf ^ 1;
    if (kt < 23) {  // issue next-tile stage FIRST (latency hides under compute)
      const int kb = (kt + 1) * 32;
      gl_lds16(srcA0 + kb, sA[nb] + dof);
      gl_lds16(srcA1 + kb, sA[nb] + 2048 + dof);
      gl_lds16(srcB0 + kb, sB[nb] + dof);
      gl_lds16(srcB1 + kb, sB[nb] + 2048 + dof);
    }
    bf16x8 av[4], bv[4];
#pragma unroll
    for (int i = 0; i < 4; ++i)
      av[i] = *(const bf16x8*)&sA[buf][(wr * 64 + i * 16 + lc) * 32 + lg * 8];
#pragma unroll
    for (int jn = 0; jn < 4; ++jn)
      bv[jn] = *(const bf16x8*)&sB[buf][(wc * 64 + jn * 16 + lc) * 32 + lg * 8];
#pragma unroll
    for (int i = 0; i < 4; ++i)
#pragma unroll
      for (int jn = 0; jn < 4; ++jn)
        acc[i][jn] = __builtin_amdgcn_mfma_f32_16x16x32_bf16(av[i], bv[jn], acc[i][jn], 0, 0, 0);
    __syncthreads();  // drains vmcnt: next buf staged; all waves done reading buf
    buf = nb;
  }

  if (y < 2) {
    const float qsc = (y == 0) ? 0.14433756729740643f : 1.0f;  // 48^-0.5 folded into Q
    u16* ob = (y == 0) ? Qo : Ko;
    const float4 zf4 = {0.f, 0.f, 0.f, 0.f};
#pragma unroll
    for (int i = 0; i < 4; ++i) {
      const int c0 = mbase + wr * 64 + i * 16 + lg * 4;
      const int hh = c0 / 48;
      const int d0 = c0 - hh * 48;
      const bool padw = (d0 == 44);  // this lane also owns the row's d48..63 zero pad
#pragma unroll
      for (int jn = 0; jn < 4; ++jn) {
        const int bn = nbase + wc * 64 + jn * 16 + lc;
        const int bb = bn / 576;
        const int nn = bn - bb * 576;
        u16* rowp = &ob[(((size_t)bb * 16 + hh) * 576 + nn) * 64 + d0];
        ushort4 o;
        o.x = f2bf(acc[i][jn][0] * qsc); o.y = f2bf(acc[i][jn][1] * qsc);
        o.z = f2bf(acc[i][jn][2] * qsc); o.w = f2bf(acc[i][jn][3] * qsc);
        *(ushort4*)rowp = o;
        if (padw) {  // d0==44 -> rowp+4 is d48; write 16 zero bf16 (2x16B)
          *(float4*)(rowp + 4) = zf4;
          *(float4*)(rowp + 12) = zf4;
        }
      }
    }
  } else {
#pragma unroll
    for (int i = 0; i < 4; ++i) {
      const int c0 = mbase + wr * 64 + i * 16 + lg * 4;
      const int hh = c0 / 48;
      const int d0 = c0 - hh * 48;
#pragma unroll
      for (int jn = 0; jn < 4; ++jn) {
        const int bn = nbase + wc * 64 + jn * 16 + lc;
        const int bb = bn / 576;
        const int nn = bn - bb * 576;
#pragma unroll
        for (int j = 0; j < 4; ++j)
          Vo[(((size_t)bb * 16 + hh) * 48 + d0 + j) * 576 + nn] = f2bf(acc[i][jn][j]);
      }
    }
  }
}

// ---------------- pos-attention GEMM: Og[b,h,q,d] = sum_m V[b,m,d] * posg[h,q,m] ----------------
// 128(M) x 64(N) tile -> 432 blocks (1.7/CU; was 240 at 0.94/CU = latency-exposed).
__global__ __launch_bounds__(256, 2) void pos_gemm(const u16* __restrict__ VT,
                                                   const u16* __restrict__ posg,
                                                   u16* __restrict__ O) {
  __shared__ u16 sA[2][128 * 32];
  __shared__ u16 sB[2][64 * 32];

  const int id = blockIdx.x;
  const int xcd = id & 7;
  const int local = id >> 3;        // 0..53
  const int h = xcd * 2 + local / 27;
  const int r = local % 27;
  const int mt = r / 9, nt = r % 9;

  const int mbase = mt * 128, nbase = nt * 64;
  const int tid = threadIdx.x;
  const int w = tid >> 6, lane = tid & 63;
  const int wr = w >> 1, wc = w & 1;
  const int lg = lane >> 4, lc = lane & 15;
  const int lrow = lane >> 2;
  const int lcol = (lane & 3) * 8;

  const int mA0 = mbase + w * 16 + lrow, mA1 = mA0 + 64;
  const u16* srcA0 = VT + ((size_t)((mA0 / 48) * 16 + h) * 48 + (mA0 % 48)) * 576 + lcol;
  const u16* srcA1 = VT + ((size_t)((mA1 / 48) * 16 + h) * 48 + (mA1 % 48)) * 576 + lcol;
  const u16* srcB0 = posg + (size_t)(h * 576 + nbase + w * 16 + lrow) * 576 + lcol;
  const int dof = w * 512;

  const f32x4 vzero = {0.f, 0.f, 0.f, 0.f};
  f32x4 acc[4][2];
#pragma unroll
  for (int i = 0; i < 4; ++i)
#pragma unroll
    for (int j = 0; j < 2; ++j) acc[i][j] = vzero;

  gl_lds16(srcA0, sA[0] + dof);
  gl_lds16(srcA1, sA[0] + 2048 + dof);
  gl_lds16(srcB0, sB[0] + dof);
  __syncthreads();

  int buf = 0;
  for (int kt = 0; kt < 18; ++kt) {
    const int nb = buf ^ 1;
    if (kt < 17) {
      const int kb = (kt + 1) * 32;
      gl_lds16(srcA0 + kb, sA[nb] + dof);
      gl_lds16(srcA1 + kb, sA[nb] + 2048 + dof);
      gl_lds16(srcB0 + kb, sB[nb] + dof);
    }
    bf16x8 av[4], bv[2];
#pragma unroll
    for (int i = 0; i < 4; ++i)
      av[i] = *(const bf16x8*)&sA[buf][(wr * 64 + i * 16 + lc) * 32 + lg * 8];
#pragma unroll
    for (int jn = 0; jn < 2; ++jn)
      bv[jn] = *(const bf16x8*)&sB[buf][(wc * 32 + jn * 16 + lc) * 32 + lg * 8];
#pragma unroll
    for (int i = 0; i < 4; ++i)
#pragma unroll
      for (int jn = 0; jn < 2; ++jn)
        acc[i][jn] = __builtin_amdgcn_mfma_f32_16x16x32_bf16(av[i], bv[jn], acc[i][jn], 0, 0, 0);
    __syncthreads();
    buf = nb;
  }

#pragma unroll
  for (int i = 0; i < 4; ++i) {
    const int c0 = mbase + wr * 64 + i * 16 + lg * 4;  // (b,d): 4 consecutive d in one head
    const int bb = c0 / 48;
    const int d0 = c0 - bb * 48;
#pragma unroll
    for (int jn = 0; jn < 2; ++jn) {
      const int q = nbase + wc * 32 + jn * 16 + lc;
      ushort4 o;
      o.x = f2bf(acc[i][jn][0]); o.y = f2bf(acc[i][jn][1]);
      o.z = f2bf(acc[i][jn][2]); o.w = f2bf(acc[i][jn][3]);
      *(ushort4*)&O[((size_t)(bb * 576 + q)) * 768 + h * 48 + d0] = o;
    }
  }
}

// ---------------- fused patch attention (pos part pre-added in Ow) ----------------
// 96 queries/block (wave = 3 x 16q subtiles sharing one K/V stream); grid 768 = 8 XCD x 96.
__global__ __launch_bounds__(256, 2) void attn_fused(
    const u16* __restrict__ Q, const u16* __restrict__ K, const u16* __restrict__ VT,
    const float* __restrict__ gating, u16* __restrict__ O) {
  const int id = blockIdx.x;
  const int b = id & 7;             // XCD-aligned (round-robin dispatch)
  const int local = id >> 3;        // 0..95
  const int h = local / 6;
  const int qt = local % 6;
  const int tid = threadIdx.x;
  const int w = tid >> 6, lane = tid & 63;
  const int qh = w >> 1, ks = w & 1;
  const int lg = lane >> 4, lc = lane & 15;
  const int bh = b * 16 + h;

  const u16* Qh = Q + (size_t)bh * 576 * 64;
  const u16* Kh = K + (size_t)bh * 576 * 64;
  const u16* Vh = VT + (size_t)bh * 48 * 576;

  __shared__ float red[6][64][13];    // split-k: [qh*3+qs][lane][12 acc + 1 lsum]

  const bf16x8 zer = {0, 0, 0, 0, 0, 0, 0, 0};
  const int qbase = qt * 96 + qh * 48;
  // Q as B-operand: B[k=d][q=lc]; pad rows are zero -> unconditional
  bf16x8 aq[3][2];
#pragma unroll
  for (int qs = 0; qs < 3; ++qs) {
    aq[qs][0] = *(const bf16x8*)&Qh[(qbase + qs * 16 + lc) * 64 + lg * 8];
    aq[qs][1] = *(const bf16x8*)&Qh[(qbase + qs * 16 + lc) * 64 + 32 + lg * 8];
  }

  const int kbase = ks * 288;

  bf16x8 kb[2][2][2];  // [buf][t][dhalf]; A-operand: A[key-row=lc][k=d]
#pragma unroll
  for (int t = 0; t < 2; ++t) {
    kb[0][t][0] = *(const bf16x8*)&Kh[(kbase + t * 16 + lc) * 64 + lg * 8];
    kb[0][t][1] = *(const bf16x8*)&Kh[(kbase + t * 16 + lc) * 64 + 32 + lg * 8];
  }

  const f32x4 vzero = {0.f, 0.f, 0.f, 0.f};
  f32x4 accP[3][3];
#pragma unroll
  for (int qs = 0; qs < 3; ++qs)
#pragma unroll
    for (int dt = 0; dt < 3; ++dt) accP[qs][dt] = vzero;
  float lsum[3] = {0.f, 0.f, 0.f};
  bf16x8 pfrag[3] = {zer, zer, zer};
  bf16x8 vp0 = zer, vp1 = zer, vp2 = zer;

  const int bpA = (((lg & 1) * 32) + lc) * 4;  // source lane byte addr (groups 0/2)
  const int bpB = bpA + 64;                    // +16 lanes (groups 1/3)
  const bool hiK = lg >= 2;                    // this lane's keys come from the s1 band

#pragma unroll
  for (int kc = 0; kc < 9; ++kc) {
    const int cur = kc & 1;
    const int k0 = kbase + kc * 32;
    if (kc < 8) {  // prefetch next K chunk
      const int k1 = k0 + 32;
#pragma unroll
      for (int t = 0; t < 2; ++t) {
        kb[cur ^ 1][t][0] = *(const bf16x8*)&Kh[(k1 + t * 16 + lc) * 64 + lg * 8];
        kb[cur ^ 1][t][1] = *(const bf16x8*)&Kh[(k1 + t * 16 + lc) * 64 + 32 + lg * 8];
      }
    }
    // V^T A-fragments for this chunk (consumed NEXT iteration)
    const bf16x8 vb0 = *(const bf16x8*)&Vh[lc * 576 + k0 + lg * 8];
    const bf16x8 vb1 = *(const bf16x8*)&Vh[(16 + lc) * 576 + k0 + lg * 8];
    const bf16x8 vb2 = *(const bf16x8*)&Vh[(32 + lc) * 576 + k0 + lg * 8];

    // S^T[key][q=lc] per subtile (shared kb)
    f32x4 s0[3], s1[3];
#pragma unroll
    for (int qs = 0; qs < 3; ++qs) {
      f32x4 a = vzero, c = vzero;
      a = __builtin_amdgcn_mfma_f32_16x16x32_bf16(kb[cur][0][0], aq[qs][0], a, 0, 0, 0);
      a = __builtin_amdgcn_mfma_f32_16x16x32_bf16(kb[cur][0][1], aq[qs][1], a, 0, 0, 0);
      c = __builtin_amdgcn_mfma_f32_16x16x32_bf16(kb[cur][1][0], aq[qs][0], c, 0, 0, 0);
      c = __builtin_amdgcn_mfma_f32_16x16x32_bf16(kb[cur][1][1], aq[qs][1], c, 0, 0, 0);
      s0[qs] = a; s1[qs] = c;
    }

    if (kc > 0) {  // PV of previous chunk (independent of s* -> fills pipe)
#pragma unroll
      for (int qs = 0; qs < 3; ++qs) {
        accP[qs][0] = __builtin_amdgcn_mfma_f32_16x16x32_bf16(vp0, pfrag[qs], accP[qs][0], 0, 0, 0);
        accP[qs][1] = __builtin_amdgcn_mfma_f32_16x16x32_bf16(vp1, pfrag[qs], accP[qs][1], 0, 0, 0);
        accP[qs][2] = __builtin_amdgcn_mfma_f32_16x16x32_bf16(vp2, pfrag[qs], accP[qs][2], 0, 0, 0);
      }
    }

#pragma unroll
    for (int qs = 0; qs < 3; ++qs) {
      const float p00 = __expf(s0[qs][0]), p01 = __expf(s0[qs][1]);
      const float p02 = __expf(s0[qs][2]), p03 = __expf(s0[qs][3]);
      const float p10 = __expf(s1[qs][0]), p11 = __expf(s1[qs][1]);
      const float p12 = __expf(s1[qs][2]), p13 = __expf(s1[qs][3]);
      lsum[qs] += ((p00 + p01) + (p02 + p03)) + ((p10 + p11) + (p12 + p13));

      uint32_t c0, c1, d0, d1;  // packed bf16 pairs: c = s0-band keys, d = s1-band keys
      asm("v_cvt_pk_bf16_f32 %0, %1, %2" : "=v"(c0) : "v"(p00), "v"(p01));
      asm("v_cvt_pk_bf16_f32 %0, %1, %2" : "=v"(c1) : "v"(p02), "v"(p03));
      asm("v_cvt_pk_bf16_f32 %0, %1, %2" : "=v"(d0) : "v"(p10), "v"(p11));
      asm("v_cvt_pk_bf16_f32 %0, %1, %2" : "=v"(d1) : "v"(p12), "v"(p13));

      // Redistribute: dest lane (lg,lc) needs keys lg*8..lg*8+7 of query lc.
      const int a_c0 = __builtin_amdgcn_ds_bpermute(bpA, (int)c0);
      const int a_c1 = __builtin_amdgcn_ds_bpermute(bpA, (int)c1);
      const int a_d0 = __builtin_amdgcn_ds_bpermute(bpA, (int)d0);
      const int a_d1 = __builtin_amdgcn_ds_bpermute(bpA, (int)d1);
      const int b_c0 = __builtin_amdgcn_ds_bpermute(bpB, (int)c0);
      const int b_c1 = __builtin_amdgcn_ds_bpermute(bpB, (int)c1);
      const int b_d0 = __builtin_amdgcn_ds_bpermute(bpB, (int)d0);
      const int b_d1 = __builtin_amdgcn_ds_bpermute(bpB, (int)d1);
      union { uint32_t u[4]; bf16x8 v; } pf;
      pf.u[0] = hiK ? a_d0 : a_c0;
      pf.u[1] = hiK ? a_d1 : a_c1;
      pf.u[2] = hiK ? b_d0 : b_c0;
      pf.u[3] = hiK ? b_d1 : b_c1;
      pfrag[qs] = pf.v;
    }
    vp0 = vb0; vp1 = vb1; vp2 = vb2;
  }
#pragma unroll
  for (int qs = 0; qs < 3; ++qs) {
    accP[qs][0] = __builtin_amdgcn_mfma_f32_16x16x32_bf16(vp0, pfrag[qs], accP[qs][0], 0, 0, 0);
    accP[qs][1] = __builtin_amdgcn_mfma_f32_16x16x32_bf16(vp1, pfrag[qs], accP[qs][1], 0, 0, 0);
    accP[qs][2] = __builtin_amdgcn_mfma_f32_16x16x32_bf16(vp2, pfrag[qs], accP[qs][2], 0, 0, 0);
  }

  // per-query (lc) row-sum for this k-half: reduce across the 4 lane-groups
  float ls[3];
#pragma unroll
  for (int qs = 0; qs < 3; ++qs) {
    float t = lsum[qs];
    t += __shfl_xor(t, 16, 64);
    t += __shfl_xor(t, 32, 64);
    ls[qs] = t;
  }

  if (ks == 1) {
#pragma unroll
    for (int qs = 0; qs < 3; ++qs) {
#pragma unroll
      for (int j = 0; j < 4; ++j) {
        red[qh * 3 + qs][lane][0 + j] = accP[qs][0][j];
        red[qh * 3 + qs][lane][4 + j] = accP[qs][1][j];
        red[qh * 3 + qs][lane][8 + j] = accP[qs][2][j];
      }
      red[qh * 3 + qs][lane][12] = ls[qs];
    }
  }
  __syncthreads();
  if (ks == 0) {
    const float g = 1.f / (1.f + __expf(-gating[h]));
#pragma unroll
    for (int qs = 0; qs < 3; ++qs) {
      const float linv = (1.f - g) / (ls[qs] + red[qh * 3 + qs][lane][12]);
      const int row = b * 576 + qbase + qs * 16 + lc;
#pragma unroll
      for (int dt = 0; dt < 3; ++dt) {
        const f32x4 a = accP[qs][dt];
        const size_t idx = (size_t)row * 768 + h * 48 + dt * 16 + lg * 4;
        const ushort4 old4 = *(const ushort4*)&O[idx];
        ushort4 o;
        o.x = f2bf((a[0] + red[qh * 3 + qs][lane][dt * 4 + 0]) * linv + bf2f(old4.x));
        o.y = f2bf((a[1] + red[qh * 3 + qs][lane][dt * 4 + 1]) * linv + bf2f(old4.y));
        o.z = f2bf((a[2] + red[qh * 3 + qs][lane][dt * 4 + 2]) * linv + bf2f(old4.z));
        o.w = f2bf((a[3] + red[qh * 3 + qs][lane][dt * 4 + 3]) * linv + bf2f(old4.w));
        *(ushort4*)&O[idx] = o;
      }
    }
  }
}

// ---------------- output projection: out = O @ Wproj^T + b ----------------
// 128(M) x 64(N) tile -> 432 blocks (1.7/CU; was 216 at 0.84/CU = latency-exposed).
__global__ __launch_bounds__(256, 2) void gemm_proj(const u16* __restrict__ A,
                                                    const u16* __restrict__ B,
                                                    float* __restrict__ of,
                                                    const float* __restrict__ bias) {
  __shared__ u16 sA[2][128 * 32];
  __shared__ u16 sB[2][64 * 32];

  const int mt = blockIdx.x / 72, nt = blockIdx.x % 72;
  const int mbase = mt * 128, nbase = nt * 64;
  const int tid = threadIdx.x;
  const int w = tid >> 6, lane = tid & 63;
  const int wr = w >> 1, wc = w & 1;
  const int lg = lane >> 4, lc = lane & 15;
  const int lrow = lane >> 2;
  const int lcol = (lane & 3) * 8;

  const u16* srcA0 = A + (size_t)(mbase + w * 16 + lrow) * 768 + lcol;
  const u16* srcA1 = srcA0 + (size_t)64 * 768;
  const u16* srcB0 = B + (size_t)(nbase + w * 16 + lrow) * 768 + lcol;
  const int dof = w * 512;

  const f32x4 vzero = {0.f, 0.f, 0.f, 0.f};
  f32x4 acc[4][2];
#pragma unroll
  for (int i = 0; i < 4; ++i)
#pragma unroll
    for (int j = 0; j < 2; ++j) acc[i][j] = vzero;

  gl_lds16(srcA0, sA[0] + dof);
  gl_lds16(srcA1, sA[0] + 2048 + dof);
  gl_lds16(srcB0, sB[0] + dof);
  __syncthreads();

  int buf = 0;
  for (int kt = 0; kt < 24; ++kt) {
    const int nb = buf ^ 1;
    if (kt < 23) {
      const int kb = (kt + 1) * 32;
      gl_lds16(srcA0 + kb, sA[nb] + dof);
      gl_lds16(srcA1 + kb, sA[nb] + 2048 + dof);
      gl_lds16(srcB0 + kb, sB[nb] + dof);
    }
    bf16x8 av[4], bv[2];
#pragma unroll
    for (int i = 0; i < 4; ++i)
      av[i] = *(const bf16x8*)&sA[buf][(wr * 64 + i * 16 + lc) * 32 + lg * 8];
#pragma unroll
    for (int jn = 0; jn < 2; ++jn)
      bv[jn] = *(const bf16x8*)&sB[buf][(wc * 32 + jn * 16 + lc) * 32 + lg * 8];
#pragma unroll
    for (int i = 0; i < 4; ++i)
#pragma unroll
      for (int jn = 0; jn < 2; ++jn)
        acc[i][jn] = __builtin_amdgcn_mfma_f32_16x16x32_bf16(av[i], bv[jn], acc[i][jn], 0, 0, 0);
    __syncthreads();
    buf = nb;
  }

#pragma unroll
  for (int i = 0; i < 4; ++i) {
    const int c0 = mbase + wr * 64 + i * 16 + lg * 4;
    const float4 b4 = *(const float4*)&bias[c0];
#pragma unroll
    for (int jn = 0; jn < 2; ++jn) {
      const int bn = nbase + wc * 32 + jn * 16 + lc;
      float4 o;
      o.x = acc[i][jn][0] + b4.x; o.y = acc[i][jn][1] + b4.y;
      o.z = acc[i][jn][2] + b4.z; o.w = acc[i][jn][3] + b4.w;
      *(float4*)&of[(size_t)bn * 768 + c0] = o;
    }
  }
}

// ---------------- launch ----------------
extern "C" void kernel_launch(void* const* d_in, const int* in_sizes, int n_in,
                              void* d_out, int out_size, void* d_ws, size_t ws_size,
                              hipStream_t stream) {
  const float* x      = (const float*)d_in[0];
  const float* Wq     = (const float*)d_in[1];
  const float* Wk     = (const float*)d_in[2];
  const float* Wv     = (const float*)d_in[3];
  const float* Wp     = (const float*)d_in[4];
  const float* bproj  = (const float*)d_in[5];
  const float* Wpos   = (const float*)d_in[6];
  const float* bpos   = (const float*)d_in[7];
  const float* gating = (const float*)d_in[8];
  float* out = (float*)d_out;

  char* ws = (char*)d_ws;
  u16* xb   = (u16*)(ws + 0);
  u16* wqb  = (u16*)(ws + 7077888);
  u16* wkb  = (u16*)(ws + 8257536);
  u16* wvb  = (u16*)(ws + 9437184);
  u16* wpb  = (u16*)(ws + 10616832);
  u16* Qw   = (u16*)(ws + 11796480);
  u16* Kw   = (u16*)(ws + 21233664);
  u16* VTw  = (u16*)(ws + 30670848);
  u16* Ow   = (u16*)(ws + 37748736);
  u16* posg = (u16*)(ws + 0);  // overlays xb..wvb (dead after gemm_qkv); ends exactly at wpb

  cvt_all<<<dim3(5760), dim3(256), 0, stream>>>(x, Wq, Wk, Wv, Wp, xb);
  gemm_qkv<<<dim3(216, 3), dim3(256), 0, stream>>>(wqb, wkb, wvb, xb, Qw, Kw, VTw);
  pos_soft<<<dim3(2304), dim3(256), 0, stream>>>(Wpos, bpos, gating, posg);
  pos_gemm<<<dim3(432), dim3(256), 0, stream>>>(VTw, posg, Ow);
  attn_fused<<<dim3(768), dim3(256), 0, stream>>>(Qw, Kw, VTw, gating, Ow);
  gemm_proj<<<dim3(432), dim3(256), 0, stream>>>(wpb, Ow, out, bproj);
}